// Round 6
// baseline (242.288 us; speedup 1.0000x reference)
//
#include <hip/hip_runtime.h>

// MMoE: B=16384 D=512 U=128 E=16 T=4, fp32 in/out.
// RE-ANCHOR round: moe_kernel is the round-0 PASSING kernel VERBATIM.
// Single change vs round 0: gates_kernel blocks 16 rows/wave (was 4),
// same per-row fma chain (bit-identical), round-0 gate layout [b][t*16+e].

#define Bsz 16384
#define Dd  512
#define Uu  128
#define Ee  16
#define Tt  4
#define Nn  2048   // U*E

typedef short bf16x8 __attribute__((ext_vector_type(8)));
typedef float f32x4 __attribute__((ext_vector_type(4)));

static __device__ __forceinline__ unsigned short f2bf(float f) {
    unsigned int u = __builtin_bit_cast(unsigned int, f);
    u += 0x7fffu + ((u >> 16) & 1u);   // round-to-nearest-even
    return (unsigned short)(u >> 16);
}
static __device__ __forceinline__ float bf2f(unsigned short s) {
    return __builtin_bit_cast(float, (unsigned int)s << 16);
}

// ---------------- Kernel 1: gate logits + softmax (exact f32) ----------------
// 16-lane group = (t = lane>>4, e = lane&15); each wave handles 16 consecutive
// rows (round 0 had 4). Per-row accumulation chain identical to round 0.
__global__ __launch_bounds__(256) void gates_kernel(
        const float* __restrict__ x, const float* __restrict__ gk,
        const float* __restrict__ gb, float* __restrict__ gates) {
    const int wave = threadIdx.x >> 6, lane = threadIdx.x & 63;
    const int t = lane >> 4, e = lane & 15;
    const int b = blockIdx.x * 64 + wave * 16;
    const float* __restrict__ gkt = gk + (size_t)t * (Dd * Ee) + e;
    const float* __restrict__ xr = x + (size_t)b * Dd;
    float acc[16];
    #pragma unroll
    for (int r = 0; r < 16; ++r) acc[r] = 0.f;
    #pragma unroll 2
    for (int d = 0; d < Dd; ++d) {
        const float w = gkt[d * Ee];
        #pragma unroll
        for (int r = 0; r < 16; ++r)
            acc[r] = fmaf(xr[r * Dd + d], w, acc[r]);
    }
    const float bias = gb[t * Ee + e];
    #pragma unroll
    for (int r = 0; r < 16; ++r) {
        float a = acc[r] + bias;
        float m = a;
        m = fmaxf(m, __shfl_xor(m, 1));
        m = fmaxf(m, __shfl_xor(m, 2));
        m = fmaxf(m, __shfl_xor(m, 4));
        m = fmaxf(m, __shfl_xor(m, 8));
        float p = __expf(a - m);
        float s = p;
        s += __shfl_xor(s, 1);
        s += __shfl_xor(s, 2);
        s += __shfl_xor(s, 4);
        s += __shfl_xor(s, 8);
        gates[(size_t)(b + r) * 64 + lane] = p / s;  // layout [b][t*16+e]
    }
}

// ---------------- Kernel 2: expert GEMM (bf16 MFMA) + relu + gate contraction ----------------
// ROUND-0 PASSING KERNEL, VERBATIM.
#define BM 128
#define BN 256   // = 16 u's x 16 e's (n = u*16+e)
#define BK 64
#define LDA 72   // padded row stride (shorts); 144 B = multiple of 16 B
#define LDB 72
#define LDE 264

__global__ __launch_bounds__(512) void moe_kernel(
        const float* __restrict__ x, const float* __restrict__ ek,
        const float* __restrict__ eb, const float* __restrict__ gates,
        float* __restrict__ out) {
    // staging region (sA+sB = 55296 B) overlaid later by eo (67584 B)
    __shared__ __align__(16) unsigned short smem[BM * LDE];
    unsigned short* sA = smem;             // [BM][LDA]  A tile, bf16
    unsigned short* sB = smem + BM * LDA;  // [BN][LDB]  B tile TRANSPOSED: sB[n][k]

    const int tid = threadIdx.x;
    const int wave = tid >> 6, lane = tid & 63;
    const int llo = lane & 15, lhi = lane >> 4;
    const int b0 = blockIdx.y * BM;
    const int n0 = blockIdx.x * BN;
    const int mr = (wave >> 2) * 64;  // wave row origin (2 row-groups)
    const int nc = (wave & 3) * 64;   // wave col origin (4 col-groups)

    f32x4 acc[4][4] = {};

    for (int kt = 0; kt < Dd / BK; ++kt) {
        const int k0 = kt * BK;
        __syncthreads();  // previous tile fully consumed before overwrite
        // stage A: 128x64 f32 -> bf16; 2048 float4s over 512 threads
        #pragma unroll
        for (int i = 0; i < 4; ++i) {
            int f = i * 512 + tid;
            int row = f >> 4, c4 = (f & 15) * 4;
            const float4 v = *(const float4*)(x + (size_t)(b0 + row) * Dd + k0 + c4);
            ushort4 w;
            w.x = f2bf(v.x); w.y = f2bf(v.y); w.z = f2bf(v.z); w.w = f2bf(v.w);
            *(ushort4*)(sA + row * LDA + c4) = w;
        }
        // stage B transposed: sB[n][k] <- ek[k][n0+n]; tasks = 16 k-groups x 256 n
        #pragma unroll
        for (int i = 0; i < 8; ++i) {
            int f = i * 512 + tid;
            int kg = (f >> 8) * 4, n = f & 255;
            const float* p = ek + (size_t)(k0 + kg) * Nn + n0 + n;
            ushort4 w;
            w.x = f2bf(p[0]);
            w.y = f2bf(p[(size_t)Nn]);
            w.z = f2bf(p[2 * (size_t)Nn]);
            w.w = f2bf(p[3 * (size_t)Nn]);
            *(ushort4*)(sB + n * LDB + kg) = w;
        }
        __syncthreads();
        #pragma unroll
        for (int ks = 0; ks < BK; ks += 32) {
            bf16x8 aF[4], bF[4];
            #pragma unroll
            for (int mi = 0; mi < 4; ++mi)
                aF[mi] = *(const bf16x8*)(sA + (mr + mi * 16 + llo) * LDA + ks + lhi * 8);
            #pragma unroll
            for (int ni = 0; ni < 4; ++ni)
                bF[ni] = *(const bf16x8*)(sB + (nc + ni * 16 + llo) * LDB + ks + lhi * 8);
            #pragma unroll
            for (int mi = 0; mi < 4; ++mi)
                #pragma unroll
                for (int ni = 0; ni < 4; ++ni)
                    acc[mi][ni] = __builtin_amdgcn_mfma_f32_16x16x32_bf16(
                        aF[mi], bF[ni], acc[mi][ni], 0, 0, 0);
        }
    }

    __syncthreads();  // all MFMA reads done; safe to overlay eo on staging LDS
    unsigned short* eo = smem;  // [BM][LDE] bf16 expert tile (relu'd)
    #pragma unroll
    for (int ni = 0; ni < 4; ++ni) {
        const int col = nc + ni * 16 + llo;     // C frag: col = lane&15
        const float ebv = eb[n0 + col];         // flat [u][e] == n
        #pragma unroll
        for (int mi = 0; mi < 4; ++mi) {
            #pragma unroll
            for (int j = 0; j < 4; ++j) {
                int row = mr + mi * 16 + lhi * 4 + j;  // C frag: row = (lane>>4)*4+j
                eo[row * LDE + col] = f2bf(fmaxf(acc[mi][ni][j] + ebv, 0.f));
            }
        }
    }
    __syncthreads();
    // contraction: out[t,b,u] = sum_e eo[b,u,e] * gates[b][t*16+e]
    #pragma unroll
    for (int i = 0; i < 4; ++i) {
        int f = i * 512 + tid;
        int m = f >> 4, ul = f & 15;
        const unsigned short* er = eo + m * LDE + ul * 16;
        const float* gr = gates + (size_t)(b0 + m) * 64;
        float o0 = 0.f, o1 = 0.f, o2 = 0.f, o3 = 0.f;
        #pragma unroll
        for (int e = 0; e < 16; ++e) {
            float v = bf2f(er[e]);
            o0 = fmaf(v, gr[e], o0);
            o1 = fmaf(v, gr[16 + e], o1);
            o2 = fmaf(v, gr[32 + e], o2);
            o3 = fmaf(v, gr[48 + e], o3);
        }
        size_t base = (size_t)(b0 + m) * Uu + (n0 >> 4) + ul;
        out[base] = o0;
        out[(size_t)Bsz * Uu + base] = o1;
        out[2 * (size_t)Bsz * Uu + base] = o2;
        out[3 * (size_t)Bsz * Uu + base] = o3;
    }
}

extern "C" void kernel_launch(void* const* d_in, const int* in_sizes, int n_in,
                              void* d_out, int out_size, void* d_ws, size_t ws_size,
                              hipStream_t stream) {
    const float* x  = (const float*)d_in[0];
    const float* ek = (const float*)d_in[1];
    const float* eb = (const float*)d_in[2];
    const float* gk = (const float*)d_in[3];
    const float* gb = (const float*)d_in[4];
    float* out = (float*)d_out;
    float* gates = (float*)d_ws;  // 16384*64*4 = 4 MiB of ws (round-0-proven)

    gates_kernel<<<Bsz / 64, 256, 0, stream>>>(x, gk, gb, gates);
    moe_kernel<<<dim3(Nn / BN, Bsz / BM), 512, 0, stream>>>(x, ek, eb, gates, out);
}

// Round 9
// 152.621 us; speedup vs baseline: 1.5875x; 1.5875x over previous
//
#include <hip/hip_runtime.h>

// MMoE: B=16384 D=512 U=128 E=16 T=4, fp32 in/out.
// moe_kernel: round-0 PASSING kernel VERBATIM (frozen anchor).
// gates_kernel: LDS-staged, high-occupancy rewrite; per-row d-accumulation
// order is bit-identical to rounds 0/6 (strictly sequential d).
// [Round 9 = rounds 7/8 resubmitted verbatim: both prior benches died on
//  UnresponsiveContainer (infra) before measuring anything.]

#define Bsz 16384
#define Dd  512
#define Uu  128
#define Ee  16
#define Tt  4
#define Nn  2048   // U*E

typedef short bf16x8 __attribute__((ext_vector_type(8)));
typedef float f32x4 __attribute__((ext_vector_type(4)));

static __device__ __forceinline__ unsigned short f2bf(float f) {
    unsigned int u = __builtin_bit_cast(unsigned int, f);
    u += 0x7fffu + ((u >> 16) & 1u);   // round-to-nearest-even
    return (unsigned short)(u >> 16);
}
static __device__ __forceinline__ float bf2f(unsigned short s) {
    return __builtin_bit_cast(float, (unsigned int)s << 16);
}

// ---------------- Kernel 1: gate logits + softmax (exact f32, LDS-staged) ----------------
// Block: 256 threads, 16 rows. Lane owns n = lane (t = n>>4, e = n&15);
// wave w owns rows w*4..w*4+3. d staged in 4 chunks of 128.
__global__ __launch_bounds__(256) void gates_kernel(
        const float* __restrict__ x, const float* __restrict__ gk,
        const float* __restrict__ gb, float* __restrict__ gates) {
    __shared__ __align__(16) float xl[16][128];    // 8 KB
    __shared__ __align__(16) float gkl[128][64];   // 32 KB
    const int tid = threadIdx.x;
    const int w = tid >> 6, lane = tid & 63;
    const int b0 = blockIdx.x * 16;
    float acc[4] = {0.f, 0.f, 0.f, 0.f};

    for (int c = 0; c < 4; ++c) {
        const int d0 = c * 128;
        __syncthreads();  // previous chunk consumed
        // stage x tile [16 rows][128 d]: 512 float4s over 256 threads
        #pragma unroll
        for (int p = 0; p < 2; ++p) {
            const int flat = p * 256 + tid;
            const int row = flat >> 5, c4 = (flat & 31) * 4;
            *(float4*)(&xl[row][c4]) =
                *(const float4*)(x + (size_t)(b0 + row) * Dd + d0 + c4);
        }
        // stage gk chunk transposed: gkl[dl][n] = gk[n>>4][d0+dl][n&15]
        {
            const int n = tid & 63, dl0 = tid >> 6;
            const float* gp = gk + (size_t)(n >> 4) * (Dd * Ee) + (n & 15)
                                 + (size_t)(d0 + dl0) * Ee;
            #pragma unroll
            for (int j = 0; j < 32; ++j)
                gkl[dl0 + j * 4][n] = gp[(size_t)j * 4 * Ee];
        }
        __syncthreads();
        // compute: per 4-d group: 4 w-reads (2-way alias, free) + 4 x float4
        // broadcasts + 16 fma. d order strictly ascending -> bit-identical
        // accumulation chain to rounds 0/6.
        #pragma unroll 4
        for (int dq = 0; dq < 32; ++dq) {
            float wv[4];
            #pragma unroll
            for (int q = 0; q < 4; ++q) wv[q] = gkl[dq * 4 + q][lane];
            #pragma unroll
            for (int r = 0; r < 4; ++r) {
                const float4 xv = *(const float4*)(&xl[w * 4 + r][dq * 4]);
                float a = acc[r];
                a = fmaf(xv.x, wv[0], a);
                a = fmaf(xv.y, wv[1], a);
                a = fmaf(xv.z, wv[2], a);
                a = fmaf(xv.w, wv[3], a);
                acc[r] = a;
            }
        }
    }
    const float bias = gb[lane];
    #pragma unroll
    for (int r = 0; r < 4; ++r) {
        float a = acc[r] + bias;
        float m = a;
        m = fmaxf(m, __shfl_xor(m, 1));
        m = fmaxf(m, __shfl_xor(m, 2));
        m = fmaxf(m, __shfl_xor(m, 4));
        m = fmaxf(m, __shfl_xor(m, 8));
        float p = __expf(a - m);
        float s = p;
        s += __shfl_xor(s, 1);
        s += __shfl_xor(s, 2);
        s += __shfl_xor(s, 4);
        s += __shfl_xor(s, 8);
        gates[(size_t)(b0 + w * 4 + r) * 64 + lane] = p / s;  // [b][t*16+e]
    }
}

// ---------------- Kernel 2: expert GEMM (bf16 MFMA) + relu + gate contraction ----------------
// ROUND-0 PASSING KERNEL, VERBATIM.
#define BM 128
#define BN 256   // = 16 u's x 16 e's (n = u*16+e)
#define BK 64
#define LDA 72   // padded row stride (shorts); 144 B = multiple of 16 B
#define LDB 72
#define LDE 264

__global__ __launch_bounds__(512) void moe_kernel(
        const float* __restrict__ x, const float* __restrict__ ek,
        const float* __restrict__ eb, const float* __restrict__ gates,
        float* __restrict__ out) {
    // staging region (sA+sB = 55296 B) overlaid later by eo (67584 B)
    __shared__ __align__(16) unsigned short smem[BM * LDE];
    unsigned short* sA = smem;             // [BM][LDA]  A tile, bf16
    unsigned short* sB = smem + BM * LDA;  // [BN][LDB]  B tile TRANSPOSED: sB[n][k]

    const int tid = threadIdx.x;
    const int wave = tid >> 6, lane = tid & 63;
    const int llo = lane & 15, lhi = lane >> 4;
    const int b0 = blockIdx.y * BM;
    const int n0 = blockIdx.x * BN;
    const int mr = (wave >> 2) * 64;  // wave row origin (2 row-groups)
    const int nc = (wave & 3) * 64;   // wave col origin (4 col-groups)

    f32x4 acc[4][4] = {};

    for (int kt = 0; kt < Dd / BK; ++kt) {
        const int k0 = kt * BK;
        __syncthreads();  // previous tile fully consumed before overwrite
        // stage A: 128x64 f32 -> bf16; 2048 float4s over 512 threads
        #pragma unroll
        for (int i = 0; i < 4; ++i) {
            int f = i * 512 + tid;
            int row = f >> 4, c4 = (f & 15) * 4;
            const float4 v = *(const float4*)(x + (size_t)(b0 + row) * Dd + k0 + c4);
            ushort4 w;
            w.x = f2bf(v.x); w.y = f2bf(v.y); w.z = f2bf(v.z); w.w = f2bf(v.w);
            *(ushort4*)(sA + row * LDA + c4) = w;
        }
        // stage B transposed: sB[n][k] <- ek[k][n0+n]; tasks = 16 k-groups x 256 n
        #pragma unroll
        for (int i = 0; i < 8; ++i) {
            int f = i * 512 + tid;
            int kg = (f >> 8) * 4, n = f & 255;
            const float* p = ek + (size_t)(k0 + kg) * Nn + n0 + n;
            ushort4 w;
            w.x = f2bf(p[0]);
            w.y = f2bf(p[(size_t)Nn]);
            w.z = f2bf(p[2 * (size_t)Nn]);
            w.w = f2bf(p[3 * (size_t)Nn]);
            *(ushort4*)(sB + n * LDB + kg) = w;
        }
        __syncthreads();
        #pragma unroll
        for (int ks = 0; ks < BK; ks += 32) {
            bf16x8 aF[4], bF[4];
            #pragma unroll
            for (int mi = 0; mi < 4; ++mi)
                aF[mi] = *(const bf16x8*)(sA + (mr + mi * 16 + llo) * LDA + ks + lhi * 8);
            #pragma unroll
            for (int ni = 0; ni < 4; ++ni)
                bF[ni] = *(const bf16x8*)(sB + (nc + ni * 16 + llo) * LDB + ks + lhi * 8);
            #pragma unroll
            for (int mi = 0; mi < 4; ++mi)
                #pragma unroll
                for (int ni = 0; ni < 4; ++ni)
                    acc[mi][ni] = __builtin_amdgcn_mfma_f32_16x16x32_bf16(
                        aF[mi], bF[ni], acc[mi][ni], 0, 0, 0);
        }
    }

    __syncthreads();  // all MFMA reads done; safe to overlay eo on staging LDS
    unsigned short* eo = smem;  // [BM][LDE] bf16 expert tile (relu'd)
    #pragma unroll
    for (int ni = 0; ni < 4; ++ni) {
        const int col = nc + ni * 16 + llo;     // C frag: col = lane&15
        const float ebv = eb[n0 + col];         // flat [u][e] == n
        #pragma unroll
        for (int mi = 0; mi < 4; ++mi) {
            #pragma unroll
            for (int j = 0; j < 4; ++j) {
                int row = mr + mi * 16 + lhi * 4 + j;  // C frag: row = (lane>>4)*4+j
                eo[row * LDE + col] = f2bf(fmaxf(acc[mi][ni][j] + ebv, 0.f));
            }
        }
    }
    __syncthreads();
    // contraction: out[t,b,u] = sum_e eo[b,u,e] * gates[b][t*16+e]
    #pragma unroll
    for (int i = 0; i < 4; ++i) {
        int f = i * 512 + tid;
        int m = f >> 4, ul = f & 15;
        const unsigned short* er = eo + m * LDE + ul * 16;
        const float* gr = gates + (size_t)(b0 + m) * 64;
        float o0 = 0.f, o1 = 0.f, o2 = 0.f, o3 = 0.f;
        #pragma unroll
        for (int e = 0; e < 16; ++e) {
            float v = bf2f(er[e]);
            o0 = fmaf(v, gr[e], o0);
            o1 = fmaf(v, gr[16 + e], o1);
            o2 = fmaf(v, gr[32 + e], o2);
            o3 = fmaf(v, gr[48 + e], o3);
        }
        size_t base = (size_t)(b0 + m) * Uu + (n0 >> 4) + ul;
        out[base] = o0;
        out[(size_t)Bsz * Uu + base] = o1;
        out[2 * (size_t)Bsz * Uu + base] = o2;
        out[3 * (size_t)Bsz * Uu + base] = o3;
    }
}

extern "C" void kernel_launch(void* const* d_in, const int* in_sizes, int n_in,
                              void* d_out, int out_size, void* d_ws, size_t ws_size,
                              hipStream_t stream) {
    const float* x  = (const float*)d_in[0];
    const float* ek = (const float*)d_in[1];
    const float* eb = (const float*)d_in[2];
    const float* gk = (const float*)d_in[3];
    const float* gb = (const float*)d_in[4];
    float* out = (float*)d_out;
    float* gates = (float*)d_ws;  // 16384*64*4 = 4 MiB of ws (proven)

    gates_kernel<<<Bsz / 16, 256, 0, stream>>>(x, gk, gb, gates);
    moe_kernel<<<dim3(Nn / BN, Bsz / BM), 512, 0, stream>>>(x, ek, eb, gates, out);
}

// Round 10
// 125.997 us; speedup vs baseline: 1.9230x; 1.2113x over previous
//
#include <hip/hip_runtime.h>

// MMoE: B=16384 D=512 U=128 E=16 T=4, fp32 in/out.
// moe_kernel: round-0 PASSING kernel, VERBATIM except B-staging reads
//   pre-converted ekT bf16 [n][d] (coalesced u16x8) instead of transposing
//   f32 ek in-kernel. Single-variable change vs round-9 anchor.
// gates_kernel: round-9 PASSING LDS-staged kernel VERBATIM.
// convert_kernel: ek [512][2048] f32 -> ekT [2048][512] bf16 (LDS transpose).
// ws usage: gates 4 MiB @0, ekT 2 MiB @4 MiB (total 6 MiB).

#define Bsz 16384
#define Dd  512
#define Uu  128
#define Ee  16
#define Tt  4
#define Nn  2048   // U*E

typedef short bf16x8 __attribute__((ext_vector_type(8)));
typedef float f32x4 __attribute__((ext_vector_type(4)));
typedef unsigned short u16x8 __attribute__((ext_vector_type(8)));

static __device__ __forceinline__ unsigned short f2bf(float f) {
    unsigned int u = __builtin_bit_cast(unsigned int, f);
    u += 0x7fffu + ((u >> 16) & 1u);   // round-to-nearest-even
    return (unsigned short)(u >> 16);
}
static __device__ __forceinline__ float bf2f(unsigned short s) {
    return __builtin_bit_cast(float, (unsigned int)s << 16);
}

// ---------------- Kernel 0: ek -> ekT bf16 transpose ----------------
// 256 blocks; block handles 64x64 tile: n0 = (bx&31)*64, d0 = (bx>>5)*64.
__global__ __launch_bounds__(256) void convert_kernel(
        const float* __restrict__ ek, unsigned short* __restrict__ ekT) {
    __shared__ unsigned short ts[64 * 65];
    const int bx = blockIdx.x, tid = threadIdx.x;
    const int n0 = (bx & 31) * 64, d0 = (bx >> 5) * 64;
    #pragma unroll
    for (int i = 0; i < 4; ++i) {
        int flat = i * 256 + tid;
        int dl = flat >> 4, ng = (flat & 15) * 4;
        const float4 v = *(const float4*)(ek + (size_t)(d0 + dl) * Nn + n0 + ng);
        ts[(ng + 0) * 65 + dl] = f2bf(v.x);
        ts[(ng + 1) * 65 + dl] = f2bf(v.y);
        ts[(ng + 2) * 65 + dl] = f2bf(v.z);
        ts[(ng + 3) * 65 + dl] = f2bf(v.w);
    }
    __syncthreads();
    #pragma unroll
    for (int i = 0; i < 4; ++i) {
        int flat = i * 256 + tid;
        int nl = flat >> 4, dg = (flat & 15) * 4;
        ushort4 w = make_ushort4(ts[nl * 65 + dg], ts[nl * 65 + dg + 1],
                                 ts[nl * 65 + dg + 2], ts[nl * 65 + dg + 3]);
        *(ushort4*)(ekT + (size_t)(n0 + nl) * Dd + d0 + dg) = w;
    }
}

// ---------------- Kernel 1: gate logits + softmax (exact f32, LDS-staged) ----------------
// ROUND-9 PASSING KERNEL, VERBATIM.
__global__ __launch_bounds__(256) void gates_kernel(
        const float* __restrict__ x, const float* __restrict__ gk,
        const float* __restrict__ gb, float* __restrict__ gates) {
    __shared__ __align__(16) float xl[16][128];    // 8 KB
    __shared__ __align__(16) float gkl[128][64];   // 32 KB
    const int tid = threadIdx.x;
    const int w = tid >> 6, lane = tid & 63;
    const int b0 = blockIdx.x * 16;
    float acc[4] = {0.f, 0.f, 0.f, 0.f};

    for (int c = 0; c < 4; ++c) {
        const int d0 = c * 128;
        __syncthreads();  // previous chunk consumed
        #pragma unroll
        for (int p = 0; p < 2; ++p) {
            const int flat = p * 256 + tid;
            const int row = flat >> 5, c4 = (flat & 31) * 4;
            *(float4*)(&xl[row][c4]) =
                *(const float4*)(x + (size_t)(b0 + row) * Dd + d0 + c4);
        }
        {
            const int n = tid & 63, dl0 = tid >> 6;
            const float* gp = gk + (size_t)(n >> 4) * (Dd * Ee) + (n & 15)
                                 + (size_t)(d0 + dl0) * Ee;
            #pragma unroll
            for (int j = 0; j < 32; ++j)
                gkl[dl0 + j * 4][n] = gp[(size_t)j * 4 * Ee];
        }
        __syncthreads();
        #pragma unroll 4
        for (int dq = 0; dq < 32; ++dq) {
            float wv[4];
            #pragma unroll
            for (int q = 0; q < 4; ++q) wv[q] = gkl[dq * 4 + q][lane];
            #pragma unroll
            for (int r = 0; r < 4; ++r) {
                const float4 xv = *(const float4*)(&xl[w * 4 + r][dq * 4]);
                float a = acc[r];
                a = fmaf(xv.x, wv[0], a);
                a = fmaf(xv.y, wv[1], a);
                a = fmaf(xv.z, wv[2], a);
                a = fmaf(xv.w, wv[3], a);
                acc[r] = a;
            }
        }
    }
    const float bias = gb[lane];
    #pragma unroll
    for (int r = 0; r < 4; ++r) {
        float a = acc[r] + bias;
        float m = a;
        m = fmaxf(m, __shfl_xor(m, 1));
        m = fmaxf(m, __shfl_xor(m, 2));
        m = fmaxf(m, __shfl_xor(m, 4));
        m = fmaxf(m, __shfl_xor(m, 8));
        float p = __expf(a - m);
        float s = p;
        s += __shfl_xor(s, 1);
        s += __shfl_xor(s, 2);
        s += __shfl_xor(s, 4);
        s += __shfl_xor(s, 8);
        gates[(size_t)(b0 + w * 4 + r) * 64 + lane] = p / s;  // [b][t*16+e]
    }
}

// ---------------- Kernel 2: expert GEMM (bf16 MFMA) + relu + gate contraction ----------------
// Round-0 anchor; ONLY the B-staging body changed (reads pre-converted ekT).
#define BM 128
#define BN 256   // = 16 u's x 16 e's (n = u*16+e)
#define BK 64
#define LDA 72   // padded row stride (shorts); 144 B = multiple of 16 B
#define LDB 72
#define LDE 264

__global__ __launch_bounds__(512) void moe_kernel(
        const float* __restrict__ x, const unsigned short* __restrict__ ekT,
        const float* __restrict__ eb, const float* __restrict__ gates,
        float* __restrict__ out) {
    // staging region (sA+sB = 55296 B) overlaid later by eo (67584 B)
    __shared__ __align__(16) unsigned short smem[BM * LDE];
    unsigned short* sA = smem;             // [BM][LDA]  A tile, bf16
    unsigned short* sB = smem + BM * LDA;  // [BN][LDB]  B tile: sB[n][k]

    const int tid = threadIdx.x;
    const int wave = tid >> 6, lane = tid & 63;
    const int llo = lane & 15, lhi = lane >> 4;
    const int b0 = blockIdx.y * BM;
    const int n0 = blockIdx.x * BN;
    const int mr = (wave >> 2) * 64;  // wave row origin (2 row-groups)
    const int nc = (wave & 3) * 64;   // wave col origin (4 col-groups)

    f32x4 acc[4][4] = {};

    for (int kt = 0; kt < Dd / BK; ++kt) {
        const int k0 = kt * BK;
        __syncthreads();  // previous tile fully consumed before overwrite
        // stage A: 128x64 f32 -> bf16; 2048 float4s over 512 threads (anchor verbatim)
        #pragma unroll
        for (int i = 0; i < 4; ++i) {
            int f = i * 512 + tid;
            int row = f >> 4, c4 = (f & 15) * 4;
            const float4 v = *(const float4*)(x + (size_t)(b0 + row) * Dd + k0 + c4);
            ushort4 w;
            w.x = f2bf(v.x); w.y = f2bf(v.y); w.z = f2bf(v.z); w.w = f2bf(v.w);
            *(ushort4*)(sA + row * LDA + c4) = w;
        }
        // stage B (CHANGED): sB[n][k] <- ekT[n0+n][k0..k0+63], coalesced u16x8
        #pragma unroll
        for (int i = 0; i < 4; ++i) {
            int f = i * 512 + tid;          // [0,2048)
            int n = f >> 3, kg8 = (f & 7) * 8;
            *(u16x8*)(sB + n * LDB + kg8) =
                *(const u16x8*)(ekT + (size_t)(n0 + n) * Dd + k0 + kg8);
        }
        __syncthreads();
        #pragma unroll
        for (int ks = 0; ks < BK; ks += 32) {
            bf16x8 aF[4], bF[4];
            #pragma unroll
            for (int mi = 0; mi < 4; ++mi)
                aF[mi] = *(const bf16x8*)(sA + (mr + mi * 16 + llo) * LDA + ks + lhi * 8);
            #pragma unroll
            for (int ni = 0; ni < 4; ++ni)
                bF[ni] = *(const bf16x8*)(sB + (nc + ni * 16 + llo) * LDB + ks + lhi * 8);
            #pragma unroll
            for (int mi = 0; mi < 4; ++mi)
                #pragma unroll
                for (int ni = 0; ni < 4; ++ni)
                    acc[mi][ni] = __builtin_amdgcn_mfma_f32_16x16x32_bf16(
                        aF[mi], bF[ni], acc[mi][ni], 0, 0, 0);
        }
    }

    __syncthreads();  // all MFMA reads done; safe to overlay eo on staging LDS
    unsigned short* eo = smem;  // [BM][LDE] bf16 expert tile (relu'd)
    #pragma unroll
    for (int ni = 0; ni < 4; ++ni) {
        const int col = nc + ni * 16 + llo;     // C frag: col = lane&15
        const float ebv = eb[n0 + col];         // flat [u][e] == n
        #pragma unroll
        for (int mi = 0; mi < 4; ++mi) {
            #pragma unroll
            for (int j = 0; j < 4; ++j) {
                int row = mr + mi * 16 + lhi * 4 + j;  // C frag: row = (lane>>4)*4+j
                eo[row * LDE + col] = f2bf(fmaxf(acc[mi][ni][j] + ebv, 0.f));
            }
        }
    }
    __syncthreads();
    // contraction: out[t,b,u] = sum_e eo[b,u,e] * gates[b][t*16+e]
    #pragma unroll
    for (int i = 0; i < 4; ++i) {
        int f = i * 512 + tid;
        int m = f >> 4, ul = f & 15;
        const unsigned short* er = eo + m * LDE + ul * 16;
        const float* gr = gates + (size_t)(b0 + m) * 64;
        float o0 = 0.f, o1 = 0.f, o2 = 0.f, o3 = 0.f;
        #pragma unroll
        for (int e = 0; e < 16; ++e) {
            float v = bf2f(er[e]);
            o0 = fmaf(v, gr[e], o0);
            o1 = fmaf(v, gr[16 + e], o1);
            o2 = fmaf(v, gr[32 + e], o2);
            o3 = fmaf(v, gr[48 + e], o3);
        }
        size_t base = (size_t)(b0 + m) * Uu + (n0 >> 4) + ul;
        out[base] = o0;
        out[(size_t)Bsz * Uu + base] = o1;
        out[2 * (size_t)Bsz * Uu + base] = o2;
        out[3 * (size_t)Bsz * Uu + base] = o3;
    }
}

extern "C" void kernel_launch(void* const* d_in, const int* in_sizes, int n_in,
                              void* d_out, int out_size, void* d_ws, size_t ws_size,
                              hipStream_t stream) {
    const float* x  = (const float*)d_in[0];
    const float* ek = (const float*)d_in[1];
    const float* eb = (const float*)d_in[2];
    const float* gk = (const float*)d_in[3];
    const float* gb = (const float*)d_in[4];
    float* out = (float*)d_out;

    char* wsb = (char*)d_ws;
    float* gates = (float*)wsb;                                // 4 MiB @ 0
    unsigned short* ekT = (unsigned short*)(wsb + (4u << 20)); // 2 MiB @ 4 MiB

    gates_kernel<<<Bsz / 16, 256, 0, stream>>>(x, gk, gb, gates);
    convert_kernel<<<256, 256, 0, stream>>>(ek, ekT);
    moe_kernel<<<dim3(Nn / BN, Bsz / BM), 512, 0, stream>>>(x, ekT, eb, gates, out);
}

// Round 11
// 116.443 us; speedup vs baseline: 2.0807x; 1.0821x over previous
//
#include <hip/hip_runtime.h>

// MMoE: B=16384 D=512 U=128 E=16 T=4, fp32 in/out.
// Round-10 anchor (PASSING, 126us) + ws_size-branched experiment:
//   conservative (ws < 22 MiB): round-10 kernels VERBATIM.
//   fast (ws >= 22 MiB): single change — moe A-staging reads pre-converted
//     xb bf16 (mirror of proven B-staging); convert_x produces xb.
// dur_us reveals which arm ran -> empirically determines ws_size regime.

#define Bsz 16384
#define Dd  512
#define Uu  128
#define Ee  16
#define Tt  4
#define Nn  2048   // U*E

typedef short bf16x8 __attribute__((ext_vector_type(8)));
typedef float f32x4 __attribute__((ext_vector_type(4)));
typedef unsigned short u16x8 __attribute__((ext_vector_type(8)));

static __device__ __forceinline__ unsigned short f2bf(float f) {
    unsigned int u = __builtin_bit_cast(unsigned int, f);
    u += 0x7fffu + ((u >> 16) & 1u);   // round-to-nearest-even
    return (unsigned short)(u >> 16);
}
static __device__ __forceinline__ float bf2f(unsigned short s) {
    return __builtin_bit_cast(float, (unsigned int)s << 16);
}

// ---------------- Kernel 0a (fast only): x f32 -> xb bf16, flat ----------------
__global__ __launch_bounds__(256) void convert_x(
        const float* __restrict__ x, unsigned short* __restrict__ xb) {
    size_t g = ((size_t)blockIdx.x * 256 + threadIdx.x) * 8;
    const float4 v0 = *(const float4*)(x + g);
    const float4 v1 = *(const float4*)(x + g + 4);
    u16x8 w;
    w[0] = f2bf(v0.x); w[1] = f2bf(v0.y); w[2] = f2bf(v0.z); w[3] = f2bf(v0.w);
    w[4] = f2bf(v1.x); w[5] = f2bf(v1.y); w[6] = f2bf(v1.z); w[7] = f2bf(v1.w);
    *(u16x8*)(xb + g) = w;
}

// ---------------- Kernel 0b: ek -> ekT bf16 transpose (round-10 verbatim) ----------------
__global__ __launch_bounds__(256) void convert_ek(
        const float* __restrict__ ek, unsigned short* __restrict__ ekT) {
    __shared__ unsigned short ts[64 * 65];
    const int bx = blockIdx.x, tid = threadIdx.x;
    const int n0 = (bx & 31) * 64, d0 = (bx >> 5) * 64;
    #pragma unroll
    for (int i = 0; i < 4; ++i) {
        int flat = i * 256 + tid;
        int dl = flat >> 4, ng = (flat & 15) * 4;
        const float4 v = *(const float4*)(ek + (size_t)(d0 + dl) * Nn + n0 + ng);
        ts[(ng + 0) * 65 + dl] = f2bf(v.x);
        ts[(ng + 1) * 65 + dl] = f2bf(v.y);
        ts[(ng + 2) * 65 + dl] = f2bf(v.z);
        ts[(ng + 3) * 65 + dl] = f2bf(v.w);
    }
    __syncthreads();
    #pragma unroll
    for (int i = 0; i < 4; ++i) {
        int flat = i * 256 + tid;
        int nl = flat >> 4, dg = (flat & 15) * 4;
        ushort4 w = make_ushort4(ts[nl * 65 + dg], ts[nl * 65 + dg + 1],
                                 ts[nl * 65 + dg + 2], ts[nl * 65 + dg + 3]);
        *(ushort4*)(ekT + (size_t)(n0 + nl) * Dd + d0 + dg) = w;
    }
}

// ---------------- Kernel 1: gate logits + softmax (round-9/10 verbatim) ----------------
__global__ __launch_bounds__(256) void gates_kernel(
        const float* __restrict__ x, const float* __restrict__ gk,
        const float* __restrict__ gb, float* __restrict__ gates) {
    __shared__ __align__(16) float xl[16][128];    // 8 KB
    __shared__ __align__(16) float gkl[128][64];   // 32 KB
    const int tid = threadIdx.x;
    const int w = tid >> 6, lane = tid & 63;
    const int b0 = blockIdx.x * 16;
    float acc[4] = {0.f, 0.f, 0.f, 0.f};

    for (int c = 0; c < 4; ++c) {
        const int d0 = c * 128;
        __syncthreads();  // previous chunk consumed
        #pragma unroll
        for (int p = 0; p < 2; ++p) {
            const int flat = p * 256 + tid;
            const int row = flat >> 5, c4 = (flat & 31) * 4;
            *(float4*)(&xl[row][c4]) =
                *(const float4*)(x + (size_t)(b0 + row) * Dd + d0 + c4);
        }
        {
            const int n = tid & 63, dl0 = tid >> 6;
            const float* gp = gk + (size_t)(n >> 4) * (Dd * Ee) + (n & 15)
                                 + (size_t)(d0 + dl0) * Ee;
            #pragma unroll
            for (int j = 0; j < 32; ++j)
                gkl[dl0 + j * 4][n] = gp[(size_t)j * 4 * Ee];
        }
        __syncthreads();
        #pragma unroll 4
        for (int dq = 0; dq < 32; ++dq) {
            float wv[4];
            #pragma unroll
            for (int q = 0; q < 4; ++q) wv[q] = gkl[dq * 4 + q][lane];
            #pragma unroll
            for (int r = 0; r < 4; ++r) {
                const float4 xv = *(const float4*)(&xl[w * 4 + r][dq * 4]);
                float a = acc[r];
                a = fmaf(xv.x, wv[0], a);
                a = fmaf(xv.y, wv[1], a);
                a = fmaf(xv.z, wv[2], a);
                a = fmaf(xv.w, wv[3], a);
                acc[r] = a;
            }
        }
    }
    const float bias = gb[lane];
    #pragma unroll
    for (int r = 0; r < 4; ++r) {
        float a = acc[r] + bias;
        float m = a;
        m = fmaxf(m, __shfl_xor(m, 1));
        m = fmaxf(m, __shfl_xor(m, 2));
        m = fmaxf(m, __shfl_xor(m, 4));
        m = fmaxf(m, __shfl_xor(m, 8));
        float p = __expf(a - m);
        float s = p;
        s += __shfl_xor(s, 1);
        s += __shfl_xor(s, 2);
        s += __shfl_xor(s, 4);
        s += __shfl_xor(s, 8);
        gates[(size_t)(b0 + w * 4 + r) * 64 + lane] = p / s;  // [b][t*16+e]
    }
}

// ---------------- Kernel 2: expert GEMM + relu + gate contraction ----------------
// Round-10 anchor; template XB: 1 = A-staging reads pre-converted xb bf16
// (mirror of proven B-staging), 0 = round-10 in-kernel f32->bf16 VERBATIM.
#define BM 128
#define BN 256   // = 16 u's x 16 e's (n = u*16+e)
#define BK 64
#define LDA 72   // padded row stride (shorts); 144 B = multiple of 16 B
#define LDB 72
#define LDE 264

template <int XB>
__global__ __launch_bounds__(512) void moe_kernel(
        const float* __restrict__ x, const unsigned short* __restrict__ xb,
        const unsigned short* __restrict__ ekT,
        const float* __restrict__ eb, const float* __restrict__ gates,
        float* __restrict__ out) {
    // staging region (sA+sB = 55296 B) overlaid later by eo (67584 B)
    __shared__ __align__(16) unsigned short smem[BM * LDE];
    unsigned short* sA = smem;             // [BM][LDA]  A tile, bf16
    unsigned short* sB = smem + BM * LDA;  // [BN][LDB]  B tile: sB[n][k]

    const int tid = threadIdx.x;
    const int wave = tid >> 6, lane = tid & 63;
    const int llo = lane & 15, lhi = lane >> 4;
    const int b0 = blockIdx.y * BM;
    const int n0 = blockIdx.x * BN;
    const int mr = (wave >> 2) * 64;  // wave row origin (2 row-groups)
    const int nc = (wave & 3) * 64;   // wave col origin (4 col-groups)

    f32x4 acc[4][4] = {};

    for (int kt = 0; kt < Dd / BK; ++kt) {
        const int k0 = kt * BK;
        __syncthreads();  // previous tile fully consumed before overwrite
        if constexpr (XB) {
            // stage A from xb bf16: 1024 u16x8 over 512 threads (2 iters)
            #pragma unroll
            for (int i = 0; i < 2; ++i) {
                int f = i * 512 + tid;
                int row = f >> 3, kg8 = (f & 7) * 8;
                *(u16x8*)(sA + row * LDA + kg8) =
                    *(const u16x8*)(xb + (size_t)(b0 + row) * Dd + k0 + kg8);
            }
        } else {
            // stage A: 128x64 f32 -> bf16; 2048 float4s over 512 threads
            #pragma unroll
            for (int i = 0; i < 4; ++i) {
                int f = i * 512 + tid;
                int row = f >> 4, c4 = (f & 15) * 4;
                const float4 v = *(const float4*)(x + (size_t)(b0 + row) * Dd + k0 + c4);
                ushort4 w;
                w.x = f2bf(v.x); w.y = f2bf(v.y); w.z = f2bf(v.z); w.w = f2bf(v.w);
                *(ushort4*)(sA + row * LDA + c4) = w;
            }
        }
        // stage B: sB[n][k] <- ekT[n0+n][k0..k0+63], coalesced u16x8
        #pragma unroll
        for (int i = 0; i < 4; ++i) {
            int f = i * 512 + tid;          // [0,2048)
            int n = f >> 3, kg8 = (f & 7) * 8;
            *(u16x8*)(sB + n * LDB + kg8) =
                *(const u16x8*)(ekT + (size_t)(n0 + n) * Dd + k0 + kg8);
        }
        __syncthreads();
        #pragma unroll
        for (int ks = 0; ks < BK; ks += 32) {
            bf16x8 aF[4], bF[4];
            #pragma unroll
            for (int mi = 0; mi < 4; ++mi)
                aF[mi] = *(const bf16x8*)(sA + (mr + mi * 16 + llo) * LDA + ks + lhi * 8);
            #pragma unroll
            for (int ni = 0; ni < 4; ++ni)
                bF[ni] = *(const bf16x8*)(sB + (nc + ni * 16 + llo) * LDB + ks + lhi * 8);
            #pragma unroll
            for (int mi = 0; mi < 4; ++mi)
                #pragma unroll
                for (int ni = 0; ni < 4; ++ni)
                    acc[mi][ni] = __builtin_amdgcn_mfma_f32_16x16x32_bf16(
                        aF[mi], bF[ni], acc[mi][ni], 0, 0, 0);
        }
    }

    __syncthreads();  // all MFMA reads done; safe to overlay eo on staging LDS
    unsigned short* eo = smem;  // [BM][LDE] bf16 expert tile (relu'd)
    #pragma unroll
    for (int ni = 0; ni < 4; ++ni) {
        const int col = nc + ni * 16 + llo;     // C frag: col = lane&15
        const float ebv = eb[n0 + col];         // flat [u][e] == n
        #pragma unroll
        for (int mi = 0; mi < 4; ++mi) {
            #pragma unroll
            for (int j = 0; j < 4; ++j) {
                int row = mr + mi * 16 + lhi * 4 + j;  // C frag: row = (lane>>4)*4+j
                eo[row * LDE + col] = f2bf(fmaxf(acc[mi][ni][j] + ebv, 0.f));
            }
        }
    }
    __syncthreads();
    // contraction: out[t,b,u] = sum_e eo[b,u,e] * gates[b][t*16+e]
    #pragma unroll
    for (int i = 0; i < 4; ++i) {
        int f = i * 512 + tid;
        int m = f >> 4, ul = f & 15;
        const unsigned short* er = eo + m * LDE + ul * 16;
        const float* gr = gates + (size_t)(b0 + m) * 64;
        float o0 = 0.f, o1 = 0.f, o2 = 0.f, o3 = 0.f;
        #pragma unroll
        for (int e = 0; e < 16; ++e) {
            float v = bf2f(er[e]);
            o0 = fmaf(v, gr[e], o0);
            o1 = fmaf(v, gr[16 + e], o1);
            o2 = fmaf(v, gr[32 + e], o2);
            o3 = fmaf(v, gr[48 + e], o3);
        }
        size_t base = (size_t)(b0 + m) * Uu + (n0 >> 4) + ul;
        out[base] = o0;
        out[(size_t)Bsz * Uu + base] = o1;
        out[2 * (size_t)Bsz * Uu + base] = o2;
        out[3 * (size_t)Bsz * Uu + base] = o3;
    }
}

extern "C" void kernel_launch(void* const* d_in, const int* in_sizes, int n_in,
                              void* d_out, int out_size, void* d_ws, size_t ws_size,
                              hipStream_t stream) {
    const float* x  = (const float*)d_in[0];
    const float* ek = (const float*)d_in[1];
    const float* eb = (const float*)d_in[2];
    const float* gk = (const float*)d_in[3];
    const float* gb = (const float*)d_in[4];
    float* out = (float*)d_out;

    char* wsb = (char*)d_ws;
    float* gates = (float*)wsb;                                // 4 MiB @ 0 (proven)
    const bool fast = ws_size >= (size_t)(22u << 20);

    gates_kernel<<<Bsz / 16, 256, 0, stream>>>(x, gk, gb, gates);
    if (fast) {
        unsigned short* xb   = (unsigned short*)(wsb + (4u << 20));   // 16 MiB
        unsigned short* ekT  = (unsigned short*)(wsb + (20u << 20));  // 2 MiB
        convert_x<<<4096, 256, 0, stream>>>(x, xb);
        convert_ek<<<256, 256, 0, stream>>>(ek, ekT);
        moe_kernel<1><<<dim3(Nn / BN, Bsz / BM), 512, 0, stream>>>(
            x, xb, ekT, eb, gates, out);
    } else {
        unsigned short* ekT = (unsigned short*)(wsb + (4u << 20));    // 2 MiB @ 4 MiB
        convert_ek<<<256, 256, 0, stream>>>(ek, ekT);
        moe_kernel<0><<<dim3(Nn / BN, Bsz / BM), 512, 0, stream>>>(
            x, (const unsigned short*)nullptr, ekT, eb, gates, out);
    }
}

// Round 12
// 100.653 us; speedup vs baseline: 2.4071x; 1.1569x over previous
//
#include <hip/hip_runtime.h>

// MMoE: B=16384 D=512 U=128 E=16 T=4, fp32 in/out.
// vs round-11 (PASSING, 116us): three value-preserving changes:
//  1. convert_x fused into gates_kernel (xb emitted from its x staging loads)
//  2. moe: XCD-aware block swizzle (bijective; 16 b0-panels x 8 n-blocks/XCD)
//  3. moe: T14 reg-prefetch (load tile kt+1 while tile kt MFMAs)
// All bf16 values, LDS layouts, accumulation orders identical to round 11.
// ws: gates 4MiB @0, xb 16MiB @4MiB, ekT 2MiB @20MiB (ws>=22MiB proven r11).

#define Bsz 16384
#define Dd  512
#define Uu  128
#define Ee  16
#define Tt  4
#define Nn  2048   // U*E

typedef short bf16x8 __attribute__((ext_vector_type(8)));
typedef float f32x4 __attribute__((ext_vector_type(4)));
typedef unsigned short u16x8 __attribute__((ext_vector_type(8)));

static __device__ __forceinline__ unsigned short f2bf(float f) {
    unsigned int u = __builtin_bit_cast(unsigned int, f);
    u += 0x7fffu + ((u >> 16) & 1u);   // round-to-nearest-even
    return (unsigned short)(u >> 16);
}
static __device__ __forceinline__ float bf2f(unsigned short s) {
    return __builtin_bit_cast(float, (unsigned int)s << 16);
}

// ---------------- Kernel 0: ek -> ekT bf16 transpose (round-10/11 verbatim) ----------------
__global__ __launch_bounds__(256) void convert_ek(
        const float* __restrict__ ek, unsigned short* __restrict__ ekT) {
    __shared__ unsigned short ts[64 * 65];
    const int bx = blockIdx.x, tid = threadIdx.x;
    const int n0 = (bx & 31) * 64, d0 = (bx >> 5) * 64;
    #pragma unroll
    for (int i = 0; i < 4; ++i) {
        int flat = i * 256 + tid;
        int dl = flat >> 4, ng = (flat & 15) * 4;
        const float4 v = *(const float4*)(ek + (size_t)(d0 + dl) * Nn + n0 + ng);
        ts[(ng + 0) * 65 + dl] = f2bf(v.x);
        ts[(ng + 1) * 65 + dl] = f2bf(v.y);
        ts[(ng + 2) * 65 + dl] = f2bf(v.z);
        ts[(ng + 3) * 65 + dl] = f2bf(v.w);
    }
    __syncthreads();
    #pragma unroll
    for (int i = 0; i < 4; ++i) {
        int flat = i * 256 + tid;
        int nl = flat >> 4, dg = (flat & 15) * 4;
        ushort4 w = make_ushort4(ts[nl * 65 + dg], ts[nl * 65 + dg + 1],
                                 ts[nl * 65 + dg + 2], ts[nl * 65 + dg + 3]);
        *(ushort4*)(ekT + (size_t)(n0 + nl) * Dd + d0 + dg) = w;
    }
}

// ---------------- Kernel 1: gates + fused x->bf16 conversion ----------------
// Round-9/10/11 gates verbatim, plus: each staged float4 of x is also
// emitted as bf16 to xb (same values moe would have converted itself).
__global__ __launch_bounds__(256) void gates_kernel(
        const float* __restrict__ x, const float* __restrict__ gk,
        const float* __restrict__ gb, float* __restrict__ gates,
        unsigned short* __restrict__ xb) {
    __shared__ __align__(16) float xl[16][128];    // 8 KB
    __shared__ __align__(16) float gkl[128][64];   // 32 KB
    const int tid = threadIdx.x;
    const int w = tid >> 6, lane = tid & 63;
    const int b0 = blockIdx.x * 16;
    float acc[4] = {0.f, 0.f, 0.f, 0.f};

    for (int c = 0; c < 4; ++c) {
        const int d0 = c * 128;
        __syncthreads();  // previous chunk consumed
        #pragma unroll
        for (int p = 0; p < 2; ++p) {
            const int flat = p * 256 + tid;
            const int row = flat >> 5, c4 = (flat & 31) * 4;
            const float4 v =
                *(const float4*)(x + (size_t)(b0 + row) * Dd + d0 + c4);
            *(float4*)(&xl[row][c4]) = v;
            // fused convert_x: identical bits to round-11's convert_x output
            *(ushort4*)(xb + (size_t)(b0 + row) * Dd + d0 + c4) =
                make_ushort4(f2bf(v.x), f2bf(v.y), f2bf(v.z), f2bf(v.w));
        }
        {
            const int n = tid & 63, dl0 = tid >> 6;
            const float* gp = gk + (size_t)(n >> 4) * (Dd * Ee) + (n & 15)
                                 + (size_t)(d0 + dl0) * Ee;
            #pragma unroll
            for (int j = 0; j < 32; ++j)
                gkl[dl0 + j * 4][n] = gp[(size_t)j * 4 * Ee];
        }
        __syncthreads();
        #pragma unroll 4
        for (int dq = 0; dq < 32; ++dq) {
            float wv[4];
            #pragma unroll
            for (int q = 0; q < 4; ++q) wv[q] = gkl[dq * 4 + q][lane];
            #pragma unroll
            for (int r = 0; r < 4; ++r) {
                const float4 xv = *(const float4*)(&xl[w * 4 + r][dq * 4]);
                float a = acc[r];
                a = fmaf(xv.x, wv[0], a);
                a = fmaf(xv.y, wv[1], a);
                a = fmaf(xv.z, wv[2], a);
                a = fmaf(xv.w, wv[3], a);
                acc[r] = a;
            }
        }
    }
    const float bias = gb[lane];
    #pragma unroll
    for (int r = 0; r < 4; ++r) {
        float a = acc[r] + bias;
        float m = a;
        m = fmaxf(m, __shfl_xor(m, 1));
        m = fmaxf(m, __shfl_xor(m, 2));
        m = fmaxf(m, __shfl_xor(m, 4));
        m = fmaxf(m, __shfl_xor(m, 8));
        float p = __expf(a - m);
        float s = p;
        s += __shfl_xor(s, 1);
        s += __shfl_xor(s, 2);
        s += __shfl_xor(s, 4);
        s += __shfl_xor(s, 8);
        gates[(size_t)(b0 + w * 4 + r) * 64 + lane] = p / s;  // [b][t*16+e]
    }
}

// ---------------- Kernel 2: expert GEMM + relu + gate contraction ----------------
// Round-11 XB=1 kernel with: 1D grid + XCD swizzle; T14 reg-prefetch.
// LDS layouts (LDA/LDB=72, eo LDE=264), MFMA phase, epilogue: VERBATIM.
#define BM 128
#define BN 256   // = 16 u's x 16 e's (n = u*16+e)
#define BK 64
#define LDA 72   // padded row stride (shorts); 144 B = multiple of 16 B
#define LDB 72
#define LDE 264

__global__ __launch_bounds__(512) void moe_kernel(
        const unsigned short* __restrict__ xb,
        const unsigned short* __restrict__ ekT,
        const float* __restrict__ eb, const float* __restrict__ gates,
        float* __restrict__ out) {
    __shared__ __align__(16) unsigned short smem[BM * LDE];
    unsigned short* sA = smem;             // [BM][LDA]  A tile, bf16
    unsigned short* sB = smem + BM * LDA;  // [BN][LDB]  B tile: sB[n][k]

    const int tid = threadIdx.x;
    const int wave = tid >> 6, lane = tid & 63;
    const int llo = lane & 15, lhi = lane >> 4;
    // XCD swizzle: bijective for 1024 blocks; XCD x gets 16 consecutive
    // b0-panels x all 8 n-blocks -> per-XCD L2 set = 2MB xb + 2MB ekT.
    const int g = (blockIdx.x & 7) * 128 + (blockIdx.x >> 3);
    const int b0 = (g >> 3) * BM;
    const int n0 = (g & 7) * BN;
    const int mr = (wave >> 2) * 64;  // wave row origin (2 row-groups)
    const int nc = (wave & 3) * 64;   // wave col origin (4 col-groups)

    f32x4 acc[4][4] = {};
    u16x8 va[2], vb[4];

    // prologue: load tile kt=0 into regs
    #pragma unroll
    for (int i = 0; i < 2; ++i) {
        int f = i * 512 + tid;
        va[i] = *(const u16x8*)(xb + (size_t)(b0 + (f >> 3)) * Dd + (f & 7) * 8);
    }
    #pragma unroll
    for (int i = 0; i < 4; ++i) {
        int f = i * 512 + tid;
        vb[i] = *(const u16x8*)(ekT + (size_t)(n0 + (f >> 3)) * Dd + (f & 7) * 8);
    }

    for (int kt = 0; kt < Dd / BK; ++kt) {
        __syncthreads();  // previous tile's MFMA reads done
        // ds_write current tile from regs (same addresses as round 11)
        #pragma unroll
        for (int i = 0; i < 2; ++i) {
            int f = i * 512 + tid;
            *(u16x8*)(sA + (f >> 3) * LDA + (f & 7) * 8) = va[i];
        }
        #pragma unroll
        for (int i = 0; i < 4; ++i) {
            int f = i * 512 + tid;
            *(u16x8*)(sB + (f >> 3) * LDB + (f & 7) * 8) = vb[i];
        }
        // T14: issue next tile's global loads; latency hides under MFMA phase
        if (kt < Dd / BK - 1) {
            const int k1 = (kt + 1) * BK;
            #pragma unroll
            for (int i = 0; i < 2; ++i) {
                int f = i * 512 + tid;
                va[i] = *(const u16x8*)(xb + (size_t)(b0 + (f >> 3)) * Dd + k1 + (f & 7) * 8);
            }
            #pragma unroll
            for (int i = 0; i < 4; ++i) {
                int f = i * 512 + tid;
                vb[i] = *(const u16x8*)(ekT + (size_t)(n0 + (f >> 3)) * Dd + k1 + (f & 7) * 8);
            }
        }
        __syncthreads();
        #pragma unroll
        for (int ks = 0; ks < BK; ks += 32) {
            bf16x8 aF[4], bF[4];
            #pragma unroll
            for (int mi = 0; mi < 4; ++mi)
                aF[mi] = *(const bf16x8*)(sA + (mr + mi * 16 + llo) * LDA + ks + lhi * 8);
            #pragma unroll
            for (int ni = 0; ni < 4; ++ni)
                bF[ni] = *(const bf16x8*)(sB + (nc + ni * 16 + llo) * LDB + ks + lhi * 8);
            #pragma unroll
            for (int mi = 0; mi < 4; ++mi)
                #pragma unroll
                for (int ni = 0; ni < 4; ++ni)
                    acc[mi][ni] = __builtin_amdgcn_mfma_f32_16x16x32_bf16(
                        aF[mi], bF[ni], acc[mi][ni], 0, 0, 0);
        }
    }

    __syncthreads();  // all MFMA reads done; safe to overlay eo on staging LDS
    unsigned short* eo = smem;  // [BM][LDE] bf16 expert tile (relu'd)
    #pragma unroll
    for (int ni = 0; ni < 4; ++ni) {
        const int col = nc + ni * 16 + llo;     // C frag: col = lane&15
        const float ebv = eb[n0 + col];         // flat [u][e] == n
        #pragma unroll
        for (int mi = 0; mi < 4; ++mi) {
            #pragma unroll
            for (int j = 0; j < 4; ++j) {
                int row = mr + mi * 16 + lhi * 4 + j;  // C frag: row = (lane>>4)*4+j
                eo[row * LDE + col] = f2bf(fmaxf(acc[mi][ni][j] + ebv, 0.f));
            }
        }
    }
    __syncthreads();
    // contraction: out[t,b,u] = sum_e eo[b,u,e] * gates[b][t*16+e]
    #pragma unroll
    for (int i = 0; i < 4; ++i) {
        int f = i * 512 + tid;
        int m = f >> 4, ul = f & 15;
        const unsigned short* er = eo + m * LDE + ul * 16;
        const float* gr = gates + (size_t)(b0 + m) * 64;
        float o0 = 0.f, o1 = 0.f, o2 = 0.f, o3 = 0.f;
        #pragma unroll
        for (int e = 0; e < 16; ++e) {
            float v = bf2f(er[e]);
            o0 = fmaf(v, gr[e], o0);
            o1 = fmaf(v, gr[16 + e], o1);
            o2 = fmaf(v, gr[32 + e], o2);
            o3 = fmaf(v, gr[48 + e], o3);
        }
        size_t base = (size_t)(b0 + m) * Uu + (n0 >> 4) + ul;
        out[base] = o0;
        out[(size_t)Bsz * Uu + base] = o1;
        out[2 * (size_t)Bsz * Uu + base] = o2;
        out[3 * (size_t)Bsz * Uu + base] = o3;
    }
}

extern "C" void kernel_launch(void* const* d_in, const int* in_sizes, int n_in,
                              void* d_out, int out_size, void* d_ws, size_t ws_size,
                              hipStream_t stream) {
    const float* x  = (const float*)d_in[0];
    const float* ek = (const float*)d_in[1];
    const float* eb = (const float*)d_in[2];
    const float* gk = (const float*)d_in[3];
    const float* gb = (const float*)d_in[4];
    float* out = (float*)d_out;

    char* wsb = (char*)d_ws;
    float* gates       = (float*)wsb;                            // 4 MiB @ 0
    unsigned short* xb  = (unsigned short*)(wsb + (4u << 20));   // 16 MiB @ 4
    unsigned short* ekT = (unsigned short*)(wsb + (20u << 20));  // 2 MiB @ 20

    gates_kernel<<<Bsz / 16, 256, 0, stream>>>(x, gk, gb, gates, xb);
    convert_ek<<<256, 256, 0, stream>>>(ek, ekT);
    moe_kernel<<<1024, 512, 0, stream>>>(xb, ekT, eb, gates, out);
}